// Round 3
// baseline (453.189 us; speedup 1.0000x reference)
//
#include <hip/hip_runtime.h>
#include <hip/hip_bf16.h>

typedef unsigned short u16;
typedef __attribute__((ext_vector_type(8))) __bf16 bf16x8;
typedef __attribute__((ext_vector_type(8))) u16 u16x8;
typedef __attribute__((ext_vector_type(4))) float f32x4;

__device__ __forceinline__ u16 f2bf(float f) {
    unsigned u = __float_as_uint(f);
    u += 0x7fffu + ((u >> 16) & 1u);   // round-to-nearest-even
    return (u16)(u >> 16);
}

// ---------- kernel 0: W1 [4][256][128] fp32 -> W1T [4][128][256] bf16 ----------
// LDS-tiled transpose: coalesced reads AND writes. grid = 4 heads x 4 d-tiles.
__global__ __launch_bounds__(256) void transpose_w1(const float* __restrict__ W1,
                                                    u16* __restrict__ W1T) {
    __shared__ u16 tile[64][132];   // 64 d x 128 k, pad to 132
    const int t = threadIdx.x;
    const int h = blockIdx.x >> 2;
    const int dt = blockIdx.x & 3;
#pragma unroll
    for (int j = 0; j < 8; ++j) {
        int idx = j * 256 + t;          // 2048 float4 slots
        int r = idx >> 5;               // d-row 0..63
        int kq = idx & 31;              // float4 col
        float4 v = *reinterpret_cast<const float4*>(
            W1 + ((size_t)h * 256 + dt * 64 + r) * 128 + kq * 4);
        ushort4 o;
        o.x = f2bf(v.x); o.y = f2bf(v.y); o.z = f2bf(v.z); o.w = f2bf(v.w);
        *reinterpret_cast<ushort4*>(&tile[r][kq * 4]) = o;
    }
    __syncthreads();
#pragma unroll
    for (int j = 0; j < 4; ++j) {
        int idx = j * 256 + t;          // 1024 u16x8 slots
        int k = idx >> 3;               // 0..127
        int c8 = idx & 7;
        u16x8 o;
#pragma unroll
        for (int e = 0; e < 8; ++e) o[e] = tile[c8 * 8 + e][k];
        *reinterpret_cast<u16x8*>(W1T + ((size_t)h * 128 + k) * 256 + dt * 64 + c8 * 8) = o;
    }
}

// ---------- kernel 1: scores[N][4] = relu(x*W1+b1)*W2 + b2 ----------
// 64-node tile, 256 thr = 4 waves; wave w = head w.
// fr-PHASED: the 128-row head tile is processed as two 64-row phases with a
// scalar partial-sum carried across phases (score = sum_r relu(.)*W2 is
// associative in r). Per-phase live set: acc[4][4]=64 + a0/a1=32 regs ->
// fits __launch_bounds__(256,3) (170-reg unified cap) -> 3 blocks/CU.
// xb: x tile as bf16, reader-linear frag order + XOR bank swizzle (verified).
// W1T A-frags read directly global->reg (L2-resident, no sharing to exploit).
// Zero barriers in the k-loops; one __syncthreads total.
__global__ __launch_bounds__(256, 3) void score_kernel(
        const float* __restrict__ x, const u16* __restrict__ W1T,
        const float* __restrict__ b1, const float* __restrict__ W2,
        const float* __restrict__ b2, float* __restrict__ scores, int N) {
    __shared__ u16 xb[16384];   // [ks 0..7][nf 0..3][slot q 0..63][8 bf16] = 32 KB

    const int t = threadIdx.x;
    const int wave = t >> 6;
    const int lane = t & 63;
    const int l15 = lane & 15;
    const int quad = lane >> 4;
    const int n0 = blockIdx.x * 64;

    // ---- per-thread W1T A-frag base (MFMA A layout: row=l15, k-chunk=quad*8).
    //      phase ph, frag j (rows ph*64 + j*16 + l15), k-step ks:
    //      ahead + ph*16384 + j*4096 + ks*32 (u16 units).
    const u16* ahead = W1T + ((size_t)wave * 128 + l15) * 256 + quad * 8;

    // ---- prefetch phase-0 first A buffer (overlaps x HBM latency)
    bf16x8 a0[4], a1[4];
#pragma unroll
    for (int j = 0; j < 4; ++j)
        a0[j] = *reinterpret_cast<const bf16x8*>(ahead + j * 4096);

    // ---- stage x tile -> xb (bf16, reader-linear + swizzle). thread t holds
    //      node = wave*16 + (lane>>2), k = i*32 + (lane&3)*8 .. +8.
    //      reader lane for this data: l_t = ((lane&3)<<4) | (lane>>2).
    {
        const int nrow = wave * 16 + (lane >> 2);
        const int koff = (lane & 3) * 8;
        int nn = n0 + nrow; if (nn >= N) nn = N - 1;     // clamp (never hits: N%64==0)
        const float* src = x + (size_t)nn * 256 + koff;
        const int l_t = ((lane & 3) << 4) | (lane >> 2);
        const int q   = l_t ^ ((l_t >> 4) << 1);         // XOR bank swizzle
        u16* dst = xb + (size_t)wave * 512 + q * 8;      // + i*2048 per chunk
        float4 v[16];
#pragma unroll
        for (int i = 0; i < 8; ++i) {
            v[2 * i]     = *reinterpret_cast<const float4*>(src + i * 32);
            v[2 * i + 1] = *reinterpret_cast<const float4*>(src + i * 32 + 4);
        }
#pragma unroll
        for (int i = 0; i < 8; ++i) {
            u16x8 o;
            o[0] = f2bf(v[2*i].x);   o[1] = f2bf(v[2*i].y);
            o[2] = f2bf(v[2*i].z);   o[3] = f2bf(v[2*i].w);
            o[4] = f2bf(v[2*i+1].x); o[5] = f2bf(v[2*i+1].y);
            o[6] = f2bf(v[2*i+1].z); o[7] = f2bf(v[2*i+1].w);
            *reinterpret_cast<u16x8*>(dst + i * 2048) = o;
        }
    }

    // ---- per-thread xb read base (swizzled, reader-linear)
    const int qr = lane ^ ((lane >> 4) << 1);
    const u16* xrd = xb + qr * 8;

    __syncthreads();    // the ONLY barrier: xb staging complete

    float p[4] = {0.f, 0.f, 0.f, 0.f};   // per-nf score partials across phases

#pragma unroll
    for (int ph = 0; ph < 2; ++ph) {
        const u16* aptr = ahead + ph * 16384;    // rows ph*64 ..
        f32x4 acc[4][4] = {};
#pragma unroll
        for (int ks = 0; ks < 8; ++ks) {
            auto& a  = (ks & 1) ? a1 : a0;
            auto& an = (ks & 1) ? a0 : a1;
            bf16x8 b[4];
#pragma unroll
            for (int nf = 0; nf < 4; ++nf)
                b[nf] = *reinterpret_cast<const bf16x8*>(xrd + (ks * 4 + nf) * 512);
            if (ks < 7) {
#pragma unroll
                for (int j = 0; j < 4; ++j)
                    an[j] = *reinterpret_cast<const bf16x8*>(
                        aptr + j * 4096 + (ks + 1) * 32);
            } else if (ph == 0) {
                // prefetch phase-1's first A buffer; its L2 latency hides
                // under phase-0's final MFMAs + partial epilogue VALU.
#pragma unroll
                for (int j = 0; j < 4; ++j)
                    an[j] = *reinterpret_cast<const bf16x8*>(ahead + 16384 + j * 4096);
            }
#pragma unroll
            for (int fr = 0; fr < 4; ++fr)
#pragma unroll
                for (int nf = 0; nf < 4; ++nf)
                    acc[fr][nf] = __builtin_amdgcn_mfma_f32_16x16x32_bf16(
                        a[fr], b[nf], acc[fr][nf], 0, 0, 0);
        }
        // ---- partial epilogue for rows ph*64 .. ph*64+63
        float4 b1v[4], w2v[4];
#pragma unroll
        for (int fr = 0; fr < 4; ++fr) {
            int rb = wave * 128 + ph * 64 + fr * 16 + quad * 4;
            b1v[fr] = *reinterpret_cast<const float4*>(b1 + rb);
            w2v[fr] = *reinterpret_cast<const float4*>(W2 + rb);
        }
#pragma unroll
        for (int nf = 0; nf < 4; ++nf) {
#pragma unroll
            for (int fr = 0; fr < 4; ++fr) {
                f32x4 c = acc[fr][nf];
                p[nf] += fmaxf(c[0] + b1v[fr].x, 0.f) * w2v[fr].x
                       + fmaxf(c[1] + b1v[fr].y, 0.f) * w2v[fr].y
                       + fmaxf(c[2] + b1v[fr].z, 0.f) * w2v[fr].z
                       + fmaxf(c[3] + b1v[fr].w, 0.f) * w2v[fr].w;
            }
        }
    }

    // ---- final reduce + store ----
    const float b2v = b2[wave];
#pragma unroll
    for (int nf = 0; nf < 4; ++nf) {
        float pp = p[nf];
        pp += __shfl_xor(pp, 16, 64);
        pp += __shfl_xor(pp, 32, 64);
        int n = n0 + nf * 16 + lane;
        if (lane < 16 && n < N)
            scores[(size_t)n * 4 + wave] = pp + b2v;
    }
}

// ---------- kernel 2: per-(graph,head) max and 1/sum(exp) ----------
__device__ __forceinline__ int lower_bound(const int* __restrict__ a, int n, int v) {
    int lo = 0, hi = n;
    while (lo < hi) {
        int mid = (lo + hi) >> 1;
        if (a[mid] < v) lo = mid + 1; else hi = mid;
    }
    return lo;
}

__global__ __launch_bounds__(256) void segstat_kernel(
        const float4* __restrict__ scores4, const int* __restrict__ seg,
        float4* __restrict__ mOut, float4* __restrict__ isOut, int N) {
    __shared__ float4 redm[4];
    __shared__ float4 reds[4];
    const int g = blockIdx.x;
    const int t = threadIdx.x;
    const int start = lower_bound(seg, N, g);
    const int end = lower_bound(seg, N, g + 1);

    float4 mx = make_float4(-3.4e38f, -3.4e38f, -3.4e38f, -3.4e38f);
    for (int i = start + t; i < end; i += 256) {
        float4 s = scores4[i];
        mx.x = fmaxf(mx.x, s.x); mx.y = fmaxf(mx.y, s.y);
        mx.z = fmaxf(mx.z, s.z); mx.w = fmaxf(mx.w, s.w);
    }
#pragma unroll
    for (int off = 1; off < 64; off <<= 1) {
        mx.x = fmaxf(mx.x, __shfl_xor(mx.x, off, 64));
        mx.y = fmaxf(mx.y, __shfl_xor(mx.y, off, 64));
        mx.z = fmaxf(mx.z, __shfl_xor(mx.z, off, 64));
        mx.w = fmaxf(mx.w, __shfl_xor(mx.w, off, 64));
    }
    if ((t & 63) == 0) redm[t >> 6] = mx;
    __syncthreads();
    mx = redm[0];
#pragma unroll
    for (int w = 1; w < 4; ++w) {
        mx.x = fmaxf(mx.x, redm[w].x); mx.y = fmaxf(mx.y, redm[w].y);
        mx.z = fmaxf(mx.z, redm[w].z); mx.w = fmaxf(mx.w, redm[w].w);
    }

    float4 sm = make_float4(0.f, 0.f, 0.f, 0.f);
    for (int i = start + t; i < end; i += 256) {
        float4 s = scores4[i];
        sm.x += expf(s.x - mx.x); sm.y += expf(s.y - mx.y);
        sm.z += expf(s.z - mx.z); sm.w += expf(s.w - mx.w);
    }
#pragma unroll
    for (int off = 1; off < 64; off <<= 1) {
        sm.x += __shfl_xor(sm.x, off, 64);
        sm.y += __shfl_xor(sm.y, off, 64);
        sm.z += __shfl_xor(sm.z, off, 64);
        sm.w += __shfl_xor(sm.w, off, 64);
    }
    if ((t & 63) == 0) reds[t >> 6] = sm;
    __syncthreads();
    if (t == 0) {
        float4 tot = reds[0];
        for (int w = 1; w < 4; ++w) {
            tot.x += reds[w].x; tot.y += reds[w].y;
            tot.z += reds[w].z; tot.w += reds[w].w;
        }
        bool nonempty = end > start;
        float4 m_out = nonempty ? mx : make_float4(0.f, 0.f, 0.f, 0.f);
        float4 is;
        is.x = (nonempty && tot.x > 0.f) ? 1.f / tot.x : 0.f;
        is.y = (nonempty && tot.y > 0.f) ? 1.f / tot.y : 0.f;
        is.z = (nonempty && tot.z > 0.f) ? 1.f / tot.z : 0.f;
        is.w = (nonempty && tot.w > 0.f) ? 1.f / tot.w : 0.f;
        mOut[g] = m_out;
        isOut[g] = is;
    }
}

// ---------- kernel 3: out[g][d] += avg_attn[n]*x[n][d]; 64-node strips ----------
__global__ __launch_bounds__(256) void wsum_kernel(
        const float* __restrict__ x, const float4* __restrict__ scores4,
        const int* __restrict__ seg, const float4* __restrict__ mArr,
        const float4* __restrict__ isArr, float* __restrict__ out, int N) {
    __shared__ float wl[64];
    __shared__ int gl[64];
    __shared__ unsigned long long bmask_s;
    const int t = threadIdx.x;
    const int n0 = blockIdx.x * 64;
    const int cnt = min(64, N - n0);

    if (t < 64) {                         // wave 0 exactly
        int g = -1;
        float w = 0.f;
        bool bnd = false;
        if (t < cnt) {
            int n = n0 + t;
            g = seg[n];
            float4 s = scores4[n];
            float4 m = mArr[g];
            float4 is = isArr[g];
            w = 0.25f * (expf(s.x - m.x) * is.x + expf(s.y - m.y) * is.y +
                         expf(s.z - m.z) * is.z + expf(s.w - m.w) * is.w);
            bnd = (t > 0) && (g != seg[n - 1]);
        }
        wl[t] = w;
        gl[t] = g;
        unsigned long long bm = __ballot(bnd);
        if (t == 0) bmask_s = bm;
    }
    __syncthreads();
    const unsigned long long bmask = bmask_s;

    int rs = 0;
    while (rs < cnt) {                    // wave-uniform run loop
        unsigned long long mm = (rs < 63) ? (bmask & ((~0ULL) << (rs + 1))) : 0ULL;
        int re = mm ? (__ffsll((long long)mm) - 1) : cnt;
        if (re > cnt) re = cnt;
        float acc = 0.f;
        int i = rs;
        for (; i + 8 <= re; i += 8) {
            float xv[8];
#pragma unroll
            for (int j = 0; j < 8; ++j)
                xv[j] = x[(size_t)(n0 + i + j) * 256 + t];
#pragma unroll
            for (int j = 0; j < 8; ++j) acc += wl[i + j] * xv[j];
        }
        for (; i < re; ++i) acc += wl[i] * x[(size_t)(n0 + i) * 256 + t];
        atomicAdd(&out[(size_t)gl[rs] * 256 + t], acc);
        rs = re;
    }
}

extern "C" void kernel_launch(void* const* d_in, const int* in_sizes, int n_in,
                              void* d_out, int out_size, void* d_ws, size_t ws_size,
                              hipStream_t stream) {
    const float* x  = (const float*)d_in[0];
    const int* seg  = (const int*)d_in[1];
    // d_in[2] = num_graphs scalar (G=1024, fixed by problem)
    const float* W1 = (const float*)d_in[3];
    const float* b1 = (const float*)d_in[4];
    const float* W2 = (const float*)d_in[5];
    const float* b2 = (const float*)d_in[6];
    float* out = (float*)d_out;

    const int N = in_sizes[0] / 256;     // 200000
    const int G = 1024;

    char* ws = (char*)d_ws;
    float* scores = (float*)ws;                                  // N*4 fp32 = 3.2 MB
    u16* W1T      = (u16*)(ws + (size_t)N * 16);                 // 131072 u16 = 256 KB
    float* mArr   = (float*)(ws + (size_t)N * 16 + 262144);      // G*4 fp32
    float* isArr  = mArr + (size_t)G * 4;                        // G*4 fp32

    hipMemsetAsync(d_out, 0, (size_t)G * 256 * sizeof(float), stream);
    transpose_w1<<<16, 256, 0, stream>>>(W1, W1T);
    score_kernel<<<(N + 63) / 64, 256, 0, stream>>>(x, W1T, b1, W2, b2, scores, N);
    segstat_kernel<<<G, 256, 0, stream>>>((const float4*)scores, seg,
                                          (float4*)mArr, (float4*)isArr, N);
    wsum_kernel<<<(N + 63) / 64, 256, 0, stream>>>(x, (const float4*)scores, seg,
                                                   (const float4*)mArr,
                                                   (const float4*)isArr, out, N);
}

// Round 5
// 435.063 us; speedup vs baseline: 1.0417x; 1.0417x over previous
//
#include <hip/hip_runtime.h>
#include <hip/hip_bf16.h>

typedef unsigned short u16;
typedef __attribute__((ext_vector_type(8))) __bf16 bf16x8;
typedef __attribute__((ext_vector_type(8))) u16 u16x8;
typedef __attribute__((ext_vector_type(4))) float f32x4;

__device__ __forceinline__ u16 f2bf(float f) {
    unsigned u = __float_as_uint(f);
    u += 0x7fffu + ((u >> 16) & 1u);   // round-to-nearest-even
    return (u16)(u >> 16);
}

__device__ __forceinline__ void gl_lds16(const void* g, void* l) {
    // direct global->LDS DMA, 16B/lane; LDS dest = wave-uniform base + lane*16
    __builtin_amdgcn_global_load_lds(
        (const __attribute__((address_space(1))) void*)g,
        (__attribute__((address_space(3))) void*)l, 16, 0, 0);
}

// ---------- kernel 0: W1 [4][256][128] fp32 -> W1T [4][128][256] bf16 ----------
__global__ __launch_bounds__(256) void transpose_w1(const float* __restrict__ W1,
                                                    u16* __restrict__ W1T) {
    __shared__ u16 tile[64][132];   // 64 d x 128 k, pad to 132
    const int t = threadIdx.x;
    const int h = blockIdx.x >> 2;
    const int dt = blockIdx.x & 3;
#pragma unroll
    for (int j = 0; j < 8; ++j) {
        int idx = j * 256 + t;          // 2048 float4 slots
        int r = idx >> 5;               // d-row 0..63
        int kq = idx & 31;              // float4 col
        float4 v = *reinterpret_cast<const float4*>(
            W1 + ((size_t)h * 256 + dt * 64 + r) * 128 + kq * 4);
        ushort4 o;
        o.x = f2bf(v.x); o.y = f2bf(v.y); o.z = f2bf(v.z); o.w = f2bf(v.w);
        *reinterpret_cast<ushort4*>(&tile[r][kq * 4]) = o;
    }
    __syncthreads();
#pragma unroll
    for (int j = 0; j < 4; ++j) {
        int idx = j * 256 + t;          // 1024 u16x8 slots
        int k = idx >> 3;               // 0..127
        int c8 = idx & 7;
        u16x8 o;
#pragma unroll
        for (int e = 0; e < 8; ++e) o[e] = tile[c8 * 8 + e][k];
        *reinterpret_cast<u16x8*>(W1T + ((size_t)h * 128 + k) * 256 + dt * 64 + c8 * 8) = o;
    }
}

// ---------- kernel 1: scores[N][4] = relu(x*W1+b1)*W2 + b2 ----------
// global_load_lds A-staging into wave-PRIVATE, 3-buffered sA (32 KB/buffer —
// 4 waves x 8 frags x 1 KB; round-4 bug was 16 KB buffers -> overflow).
// No barriers in the k-loop: per-wave counted s_waitcnt vmcnt keeps 2
// k-steps of staging in flight. sA slot s holds reader-lane s's frag
// (source pre-swizzled: row = s&15, kc = (s>>4)*8), so the ds_read_b128 is
// 64 consecutive 16B slots = conflict-free. xb: verified reader-linear +
// XOR-swizzle layout. 128 KB LDS -> 1 block/CU; launch_bounds(256,1) gives
// the compiler the full VGPR file (no spill).
__global__ __launch_bounds__(256, 1) void score_kernel(
        const float* __restrict__ x, const u16* __restrict__ W1T,
        const float* __restrict__ b1, const float* __restrict__ W2,
        const float* __restrict__ b2, float* __restrict__ scores, int N) {
    __shared__ u16 xb[16384];       // [ks][nf][slot q][8 bf16] = 32 KB
    __shared__ u16 sA[3][16384];    // 3 bufs x [fr 0..31][slot 0..63][8] = 96 KB

    const int t = threadIdx.x;
    const int wave = t >> 6;
    const int lane = t & 63;
    const int l15 = lane & 15;
    const int quad = lane >> 4;
    const int n0 = blockIdx.x * 64;

    // ---- swizzled global source for A staging: lane s supplies the frag that
    //      READER lane s needs: row = fr*16 + (s&15), k-chunk = (s>>4)*8.
    //      per j: +j*4096 (16 rows); per ks: +ks*32.
    const u16* asrc = W1T + ((size_t)wave * 128 + l15) * 256 + quad * 8;

    // ---- stage x tile -> xb (bf16, reader-linear + XOR swizzle; verified r2).
    {
        const int nrow = wave * 16 + (lane >> 2);
        const int koff = (lane & 3) * 8;
        int nn = n0 + nrow; if (nn >= N) nn = N - 1;     // clamp (never hits: N%64==0)
        const float* src = x + (size_t)nn * 256 + koff;
        const int l_t = ((lane & 3) << 4) | (lane >> 2);
        const int q   = l_t ^ ((l_t >> 4) << 1);         // XOR bank swizzle
        u16* dst = xb + (size_t)wave * 512 + q * 8;      // + i*2048 per chunk
        float4 v[16];
#pragma unroll
        for (int i = 0; i < 8; ++i) {
            v[2 * i]     = *reinterpret_cast<const float4*>(src + i * 32);
            v[2 * i + 1] = *reinterpret_cast<const float4*>(src + i * 32 + 4);
        }
#pragma unroll
        for (int i = 0; i < 8; ++i) {
            u16x8 o;
            o[0] = f2bf(v[2*i].x);   o[1] = f2bf(v[2*i].y);
            o[2] = f2bf(v[2*i].z);   o[3] = f2bf(v[2*i].w);
            o[4] = f2bf(v[2*i+1].x); o[5] = f2bf(v[2*i+1].y);
            o[6] = f2bf(v[2*i+1].z); o[7] = f2bf(v[2*i+1].w);
            *reinterpret_cast<u16x8*>(dst + i * 2048) = o;
        }
    }

    const int qr = lane ^ ((lane >> 4) << 1);
    const u16* xrd = xb + qr * 8;

    __syncthreads();    // the ONLY barrier: xb staging complete

    // ---- issue 2-deep A prefetch AFTER the barrier (so the barrier's
    //      vmcnt(0) drain doesn't flatten the pipeline).
#pragma unroll
    for (int j = 0; j < 8; ++j)
        gl_lds16(asrc + j * 4096, &sA[0][(wave * 8 + j) * 512]);
#pragma unroll
    for (int j = 0; j < 8; ++j)
        gl_lds16(asrc + j * 4096 + 32, &sA[1][(wave * 8 + j) * 512]);

    f32x4 acc[8][4] = {};
#pragma unroll
    for (int ks = 0; ks < 8; ++ks) {
        if (ks < 6) {               // stage ks+2 into buf (ks+2)%3
            const int buf = (ks + 2) % 3;
#pragma unroll
            for (int j = 0; j < 8; ++j)
                gl_lds16(asrc + j * 4096 + (ks + 2) * 32,
                         &sA[buf][(wave * 8 + j) * 512]);
        }
        // per-wave counted wait: ensure stage(ks) has landed, keep rest in flight
        if (ks < 6)      asm volatile("s_waitcnt vmcnt(16)" ::: "memory");
        else if (ks == 6) asm volatile("s_waitcnt vmcnt(8)" ::: "memory");
        else              asm volatile("s_waitcnt vmcnt(0)" ::: "memory");
        __builtin_amdgcn_sched_barrier(0);

        bf16x8 a[8], b[4];
        const u16* abase = &sA[ks % 3][wave * 4096 + lane * 8];
#pragma unroll
        for (int j = 0; j < 8; ++j)
            a[j] = *reinterpret_cast<const bf16x8*>(abase + j * 512);
#pragma unroll
        for (int nf = 0; nf < 4; ++nf)
            b[nf] = *reinterpret_cast<const bf16x8*>(xrd + (ks * 4 + nf) * 512);
#pragma unroll
        for (int fr = 0; fr < 8; ++fr)
#pragma unroll
            for (int nf = 0; nf < 4; ++nf)
                acc[fr][nf] = __builtin_amdgcn_mfma_f32_16x16x32_bf16(
                    a[fr], b[nf], acc[fr][nf], 0, 0, 0);
    }

    // ---- epilogue: score = sum_r relu(acc + b1)*W2, in-wave only ----
    const int h = wave;
    float4 b1v[8], w2v[8];
#pragma unroll
    for (int fr = 0; fr < 8; ++fr) {
        int rb = h * 128 + fr * 16 + quad * 4;
        b1v[fr] = *reinterpret_cast<const float4*>(b1 + rb);
        w2v[fr] = *reinterpret_cast<const float4*>(W2 + rb);
    }
    const float b2v = b2[h];
#pragma unroll
    for (int nf = 0; nf < 4; ++nf) {
        float p = 0.f;
#pragma unroll
        for (int fr = 0; fr < 8; ++fr) {
            f32x4 c = acc[fr][nf];
            p += fmaxf(c[0] + b1v[fr].x, 0.f) * w2v[fr].x
               + fmaxf(c[1] + b1v[fr].y, 0.f) * w2v[fr].y
               + fmaxf(c[2] + b1v[fr].z, 0.f) * w2v[fr].z
               + fmaxf(c[3] + b1v[fr].w, 0.f) * w2v[fr].w;
        }
        p += __shfl_xor(p, 16, 64);
        p += __shfl_xor(p, 32, 64);
        int n = n0 + nf * 16 + lane;
        if (lane < 16 && n < N)
            scores[(size_t)n * 4 + h] = p + b2v;
    }
}

// ---------- kernel 2: per-(graph,head) max and 1/sum(exp) ----------
__device__ __forceinline__ int lower_bound(const int* __restrict__ a, int n, int v) {
    int lo = 0, hi = n;
    while (lo < hi) {
        int mid = (lo + hi) >> 1;
        if (a[mid] < v) lo = mid + 1; else hi = mid;
    }
    return lo;
}

__global__ __launch_bounds__(256) void segstat_kernel(
        const float4* __restrict__ scores4, const int* __restrict__ seg,
        float4* __restrict__ mOut, float4* __restrict__ isOut, int N) {
    __shared__ float4 redm[4];
    __shared__ float4 reds[4];
    const int g = blockIdx.x;
    const int t = threadIdx.x;
    const int start = lower_bound(seg, N, g);
    const int end = lower_bound(seg, N, g + 1);

    float4 mx = make_float4(-3.4e38f, -3.4e38f, -3.4e38f, -3.4e38f);
    for (int i = start + t; i < end; i += 256) {
        float4 s = scores4[i];
        mx.x = fmaxf(mx.x, s.x); mx.y = fmaxf(mx.y, s.y);
        mx.z = fmaxf(mx.z, s.z); mx.w = fmaxf(mx.w, s.w);
    }
#pragma unroll
    for (int off = 1; off < 64; off <<= 1) {
        mx.x = fmaxf(mx.x, __shfl_xor(mx.x, off, 64));
        mx.y = fmaxf(mx.y, __shfl_xor(mx.y, off, 64));
        mx.z = fmaxf(mx.z, __shfl_xor(mx.z, off, 64));
        mx.w = fmaxf(mx.w, __shfl_xor(mx.w, off, 64));
    }
    if ((t & 63) == 0) redm[t >> 6] = mx;
    __syncthreads();
    mx = redm[0];
#pragma unroll
    for (int w = 1; w < 4; ++w) {
        mx.x = fmaxf(mx.x, redm[w].x); mx.y = fmaxf(mx.y, redm[w].y);
        mx.z = fmaxf(mx.z, redm[w].z); mx.w = fmaxf(mx.w, redm[w].w);
    }

    float4 sm = make_float4(0.f, 0.f, 0.f, 0.f);
    for (int i = start + t; i < end; i += 256) {
        float4 s = scores4[i];
        sm.x += expf(s.x - mx.x); sm.y += expf(s.y - mx.y);
        sm.z += expf(s.z - mx.z); sm.w += expf(s.w - mx.w);
    }
#pragma unroll
    for (int off = 1; off < 64; off <<= 1) {
        sm.x += __shfl_xor(sm.x, off, 64);
        sm.y += __shfl_xor(sm.y, off, 64);
        sm.z += __shfl_xor(sm.z, off, 64);
        sm.w += __shfl_xor(sm.w, off, 64);
    }
    if ((t & 63) == 0) reds[t >> 6] = sm;
    __syncthreads();
    if (t == 0) {
        float4 tot = reds[0];
        for (int w = 1; w < 4; ++w) {
            tot.x += reds[w].x; tot.y += reds[w].y;
            tot.z += reds[w].z; tot.w += reds[w].w;
        }
        bool nonempty = end > start;
        float4 m_out = nonempty ? mx : make_float4(0.f, 0.f, 0.f, 0.f);
        float4 is;
        is.x = (nonempty && tot.x > 0.f) ? 1.f / tot.x : 0.f;
        is.y = (nonempty && tot.y > 0.f) ? 1.f / tot.y : 0.f;
        is.z = (nonempty && tot.z > 0.f) ? 1.f / tot.z : 0.f;
        is.w = (nonempty && tot.w > 0.f) ? 1.f / tot.w : 0.f;
        mOut[g] = m_out;
        isOut[g] = is;
    }
}

// ---------- kernel 3: out[g][d] += avg_attn[n]*x[n][d]; 64-node strips ----------
__global__ __launch_bounds__(256) void wsum_kernel(
        const float* __restrict__ x, const float4* __restrict__ scores4,
        const int* __restrict__ seg, const float4* __restrict__ mArr,
        const float4* __restrict__ isArr, float* __restrict__ out, int N) {
    __shared__ float wl[64];
    __shared__ int gl[64];
    __shared__ unsigned long long bmask_s;
    const int t = threadIdx.x;
    const int n0 = blockIdx.x * 64;
    const int cnt = min(64, N - n0);

    if (t < 64) {                         // wave 0 exactly
        int g = -1;
        float w = 0.f;
        bool bnd = false;
        if (t < cnt) {
            int n = n0 + t;
            g = seg[n];
            float4 s = scores4[n];
            float4 m = mArr[g];
            float4 is = isArr[g];
            w = 0.25f * (expf(s.x - m.x) * is.x + expf(s.y - m.y) * is.y +
                         expf(s.z - m.z) * is.z + expf(s.w - m.w) * is.w);
            bnd = (t > 0) && (g != seg[n - 1]);
        }
        wl[t] = w;
        gl[t] = g;
        unsigned long long bm = __ballot(bnd);
        if (t == 0) bmask_s = bm;
    }
    __syncthreads();
    const unsigned long long bmask = bmask_s;

    int rs = 0;
    while (rs < cnt) {                    // wave-uniform run loop
        unsigned long long mm = (rs < 63) ? (bmask & ((~0ULL) << (rs + 1))) : 0ULL;
        int re = mm ? (__ffsll((long long)mm) - 1) : cnt;
        if (re > cnt) re = cnt;
        float acc = 0.f;
        int i = rs;
        for (; i + 8 <= re; i += 8) {
            float xv[8];
#pragma unroll
            for (int j = 0; j < 8; ++j)
                xv[j] = x[(size_t)(n0 + i + j) * 256 + t];
#pragma unroll
            for (int j = 0; j < 8; ++j) acc += wl[i + j] * xv[j];
        }
        for (; i < re; ++i) acc += wl[i] * x[(size_t)(n0 + i) * 256 + t];
        atomicAdd(&out[(size_t)gl[rs] * 256 + t], acc);
        rs = re;
    }
}

extern "C" void kernel_launch(void* const* d_in, const int* in_sizes, int n_in,
                              void* d_out, int out_size, void* d_ws, size_t ws_size,
                              hipStream_t stream) {
    const float* x  = (const float*)d_in[0];
    const int* seg  = (const int*)d_in[1];
    // d_in[2] = num_graphs scalar (G=1024, fixed by problem)
    const float* W1 = (const float*)d_in[3];
    const float* b1 = (const float*)d_in[4];
    const float* W2 = (const float*)d_in[5];
    const float* b2 = (const float*)d_in[6];
    float* out = (float*)d_out;

    const int N = in_sizes[0] / 256;     // 200000
    const int G = 1024;

    char* ws = (char*)d_ws;
    float* scores = (float*)ws;                                  // N*4 fp32 = 3.2 MB
    u16* W1T      = (u16*)(ws + (size_t)N * 16);                 // 131072 u16 = 256 KB
    float* mArr   = (float*)(ws + (size_t)N * 16 + 262144);      // G*4 fp32
    float* isArr  = mArr + (size_t)G * 4;                        // G*4 fp32

    hipMemsetAsync(d_out, 0, (size_t)G * 256 * sizeof(float), stream);
    transpose_w1<<<16, 256, 0, stream>>>(W1, W1T);
    score_kernel<<<(N + 63) / 64, 256, 0, stream>>>(x, W1T, b1, W2, b2, scores, N);
    segstat_kernel<<<G, 256, 0, stream>>>((const float4*)scores, seg,
                                          (float4*)mArr, (float4*)isArr, N);
    wsum_kernel<<<(N + 63) / 64, 256, 0, stream>>>(x, (const float4*)scores, seg,
                                                   (const float4*)mArr,
                                                   (const float4*)isArr, out, N);
}

// Round 6
// 408.591 us; speedup vs baseline: 1.1092x; 1.0648x over previous
//
#include <hip/hip_runtime.h>
#include <hip/hip_bf16.h>

typedef unsigned short u16;
typedef __attribute__((ext_vector_type(8))) __bf16 bf16x8;
typedef __attribute__((ext_vector_type(8))) u16 u16x8;
typedef __attribute__((ext_vector_type(4))) float f32x4;

__device__ __forceinline__ u16 f2bf(float f) {
    unsigned u = __float_as_uint(f);
    u += 0x7fffu + ((u >> 16) & 1u);   // round-to-nearest-even
    return (u16)(u >> 16);
}

__device__ __forceinline__ void gl_lds16(const void* g, void* l) {
    // direct global->LDS DMA, 16B/lane; LDS dest = wave-uniform base + lane*16
    __builtin_amdgcn_global_load_lds(
        (const __attribute__((address_space(1))) void*)g,
        (__attribute__((address_space(3))) void*)l, 16, 0, 0);
}

// ---------- kernel 0: W1 [4][256][128] fp32 -> W1T [4][128][256] bf16 ----------
__global__ __launch_bounds__(256) void transpose_w1(const float* __restrict__ W1,
                                                    u16* __restrict__ W1T) {
    __shared__ u16 tile[64][132];   // 64 d x 128 k, pad to 132
    const int t = threadIdx.x;
    const int h = blockIdx.x >> 2;
    const int dt = blockIdx.x & 3;
#pragma unroll
    for (int j = 0; j < 8; ++j) {
        int idx = j * 256 + t;          // 2048 float4 slots
        int r = idx >> 5;               // d-row 0..63
        int kq = idx & 31;              // float4 col
        float4 v = *reinterpret_cast<const float4*>(
            W1 + ((size_t)h * 256 + dt * 64 + r) * 128 + kq * 4);
        ushort4 o;
        o.x = f2bf(v.x); o.y = f2bf(v.y); o.z = f2bf(v.z); o.w = f2bf(v.w);
        *reinterpret_cast<ushort4*>(&tile[r][kq * 4]) = o;
    }
    __syncthreads();
#pragma unroll
    for (int j = 0; j < 4; ++j) {
        int idx = j * 256 + t;          // 1024 u16x8 slots
        int k = idx >> 3;               // 0..127
        int c8 = idx & 7;
        u16x8 o;
#pragma unroll
        for (int e = 0; e < 8; ++e) o[e] = tile[c8 * 8 + e][k];
        *reinterpret_cast<u16x8*>(W1T + ((size_t)h * 128 + k) * 256 + dt * 64 + c8 * 8) = o;
    }
}

// ---------- kernel 1: scores[N][4] = relu(x*W1+b1)*W2 + b2 ----------
// ROUND-0 structure exactly (proven 131.7 us: 64 KB LDS -> 2 blocks/CU,
// single sA buffer, 2 __syncthreads per k-step, global_load_lds staging),
// plus the two conflict-free layouts verified in r2/r3/r5:
//  - xb: reader-linear frag order + XOR bank swizzle (slot q = l ^ ((l>>4)<<1))
//  - sA: source pre-swizzled so DMA slot s holds reader-lane s's frag
//    (row = fr*16 + (s&15), kc = (s>>4)*8); read is lane-linear 16B slots.
// Both read patterns are 64 consecutive 16B slots / wave = free 2-way aliasing.
__global__ __launch_bounds__(256, 2) void score_kernel(
        const float* __restrict__ x, const u16* __restrict__ W1T,
        const float* __restrict__ b1, const float* __restrict__ W2,
        const float* __restrict__ b2, float* __restrict__ scores, int N) {
    __shared__ u16 xb[16384];   // [ks 0..7][nf 0..3][slot q 0..63][8 bf16] = 32 KB
    __shared__ u16 sA[16384];   // [fr 0..31][slot 0..63][8 bf16]           = 32 KB

    const int t = threadIdx.x;
    const int wave = t >> 6;
    const int lane = t & 63;
    const int l15 = lane & 15;
    const int quad = lane >> 4;
    const int n0 = blockIdx.x * 64;

    // ---- swizzled global source for A staging: lane s supplies the frag that
    //      reader lane s needs. per j: +j*4096 (16 rows); per ks: +ks*32.
    const u16* asrc = W1T + ((size_t)wave * 128 + l15) * 256 + quad * 8;

    auto stageA = [&](int ks) {
#pragma unroll
        for (int j = 0; j < 8; ++j)
            gl_lds16(asrc + j * 4096 + ks * 32, &sA[(size_t)(wave * 8 + j) * 512]);
    };

    stageA(0);   // DMA overlaps the x staging below

    // ---- stage x tile -> xb (bf16, reader-linear + XOR swizzle; verified).
    {
        const int nrow = wave * 16 + (lane >> 2);
        const int koff = (lane & 3) * 8;
        int nn = n0 + nrow; if (nn >= N) nn = N - 1;     // clamp (never hits: N%64==0)
        const float* src = x + (size_t)nn * 256 + koff;
        const int l_t = ((lane & 3) << 4) | (lane >> 2);
        const int q   = l_t ^ ((l_t >> 4) << 1);         // XOR bank swizzle
        u16* dst = xb + (size_t)wave * 512 + q * 8;      // + i*2048 per chunk
        float4 v[16];
#pragma unroll
        for (int i = 0; i < 8; ++i) {
            v[2 * i]     = *reinterpret_cast<const float4*>(src + i * 32);
            v[2 * i + 1] = *reinterpret_cast<const float4*>(src + i * 32 + 4);
        }
#pragma unroll
        for (int i = 0; i < 8; ++i) {
            u16x8 o;
            o[0] = f2bf(v[2*i].x);   o[1] = f2bf(v[2*i].y);
            o[2] = f2bf(v[2*i].z);   o[3] = f2bf(v[2*i].w);
            o[4] = f2bf(v[2*i+1].x); o[5] = f2bf(v[2*i+1].y);
            o[6] = f2bf(v[2*i+1].z); o[7] = f2bf(v[2*i+1].w);
            *reinterpret_cast<u16x8*>(dst + i * 2048) = o;
        }
    }

    const int qr = lane ^ ((lane >> 4) << 1);
    const u16* xrd = xb + qr * 8;
    const u16* abase = &sA[(size_t)wave * 4096 + lane * 8];

    __syncthreads();    // xb + sA(0) staging complete

    f32x4 acc[8][4] = {};
    for (int ks = 0; ks < 8; ++ks) {
        bf16x8 a[8], b[4];
#pragma unroll
        for (int j = 0; j < 8; ++j)
            a[j] = *reinterpret_cast<const bf16x8*>(abase + j * 512);
#pragma unroll
        for (int nf = 0; nf < 4; ++nf)
            b[nf] = *reinterpret_cast<const bf16x8*>(xrd + (ks * 4 + nf) * 512);
        __syncthreads();                    // all waves done reading sA[ks]
        if (ks < 7) stageA(ks + 1);         // async overwrite while MFMA runs
#pragma unroll
        for (int fr = 0; fr < 8; ++fr)
#pragma unroll
            for (int nf = 0; nf < 4; ++nf)
                acc[fr][nf] = __builtin_amdgcn_mfma_f32_16x16x32_bf16(
                    a[fr], b[nf], acc[fr][nf], 0, 0, 0);
        __syncthreads();                    // vmcnt(0) drain: staging complete
    }

    // ---- epilogue: score = sum_r relu(acc + b1)*W2, in-wave only ----
    const int h = wave;
    float4 b1v[8], w2v[8];
#pragma unroll
    for (int fr = 0; fr < 8; ++fr) {
        int rb = h * 128 + fr * 16 + quad * 4;
        b1v[fr] = *reinterpret_cast<const float4*>(b1 + rb);
        w2v[fr] = *reinterpret_cast<const float4*>(W2 + rb);
    }
    const float b2v = b2[h];
#pragma unroll
    for (int nf = 0; nf < 4; ++nf) {
        float p = 0.f;
#pragma unroll
        for (int fr = 0; fr < 8; ++fr) {
            f32x4 c = acc[fr][nf];
            p += fmaxf(c[0] + b1v[fr].x, 0.f) * w2v[fr].x
               + fmaxf(c[1] + b1v[fr].y, 0.f) * w2v[fr].y
               + fmaxf(c[2] + b1v[fr].z, 0.f) * w2v[fr].z
               + fmaxf(c[3] + b1v[fr].w, 0.f) * w2v[fr].w;
        }
        p += __shfl_xor(p, 16, 64);
        p += __shfl_xor(p, 32, 64);
        int n = n0 + nf * 16 + lane;
        if (lane < 16 && n < N)
            scores[(size_t)n * 4 + h] = p + b2v;
    }
}

// ---------- kernel 2: starts[g] = lower_bound(seg, g), g = 0..G ----------
__device__ __forceinline__ int lower_bound(const int* __restrict__ a, int n, int v) {
    int lo = 0, hi = n;
    while (lo < hi) {
        int mid = (lo + hi) >> 1;
        if (a[mid] < v) lo = mid + 1; else hi = mid;
    }
    return lo;
}

__global__ __launch_bounds__(256) void starts_kernel(
        const int* __restrict__ seg, int* __restrict__ starts, int N, int G) {
    int g = blockIdx.x * 256 + threadIdx.x;
    if (g > G) return;
    if (g == 0)      starts[0] = 0;
    else if (g == G) starts[G] = N;
    else             starts[g] = lower_bound(seg, N, g);
}

// ---------- kernel 3: fused per-graph softmax + weighted sum ----------
// One block per graph. Pass 1: per-head max over the segment's scores.
// Pass 2: per-head sum(exp). Pass 3: chunked weights in LDS + weighted sum
// of x with DIRECT writes to out[g] (no atomics, no memset; empty graphs
// write zeros). Replaces segstat_kernel + wsum_kernel + memset.
__global__ __launch_bounds__(256) void pool_kernel(
        const float* __restrict__ x, const float4* __restrict__ scores4,
        const int* __restrict__ starts, float* __restrict__ out) {
    __shared__ float4 red[4];
    __shared__ float wl[256];
    const int g = blockIdx.x;
    const int t = threadIdx.x;
    const int lane = t & 63;
    const int wv = t >> 6;
    const int start = starts[g];
    const int end = starts[g + 1];
    const int len = end - start;

    float* og = out + (size_t)g * 256;
    if (len == 0) { og[t] = 0.f; return; }   // uniform across block

    // ---- pass 1: per-head max ----
    float4 mx = make_float4(-3.4e38f, -3.4e38f, -3.4e38f, -3.4e38f);
    for (int i = start + t; i < end; i += 256) {
        float4 s = scores4[i];
        mx.x = fmaxf(mx.x, s.x); mx.y = fmaxf(mx.y, s.y);
        mx.z = fmaxf(mx.z, s.z); mx.w = fmaxf(mx.w, s.w);
    }
#pragma unroll
    for (int off = 1; off < 64; off <<= 1) {
        mx.x = fmaxf(mx.x, __shfl_xor(mx.x, off, 64));
        mx.y = fmaxf(mx.y, __shfl_xor(mx.y, off, 64));
        mx.z = fmaxf(mx.z, __shfl_xor(mx.z, off, 64));
        mx.w = fmaxf(mx.w, __shfl_xor(mx.w, off, 64));
    }
    if (lane == 0) red[wv] = mx;
    __syncthreads();
    {
        float4 r0 = red[0], r1 = red[1], r2 = red[2], r3 = red[3];
        mx.x = fmaxf(fmaxf(r0.x, r1.x), fmaxf(r2.x, r3.x));
        mx.y = fmaxf(fmaxf(r0.y, r1.y), fmaxf(r2.y, r3.y));
        mx.z = fmaxf(fmaxf(r0.z, r1.z), fmaxf(r2.z, r3.z));
        mx.w = fmaxf(fmaxf(r0.w, r1.w), fmaxf(r2.w, r3.w));
    }
    __syncthreads();

    // ---- pass 2: per-head sum(exp) ----
    float4 sm = make_float4(0.f, 0.f, 0.f, 0.f);
    for (int i = start + t; i < end; i += 256) {
        float4 s = scores4[i];
        sm.x += expf(s.x - mx.x); sm.y += expf(s.y - mx.y);
        sm.z += expf(s.z - mx.z); sm.w += expf(s.w - mx.w);
    }
#pragma unroll
    for (int off = 1; off < 64; off <<= 1) {
        sm.x += __shfl_xor(sm.x, off, 64);
        sm.y += __shfl_xor(sm.y, off, 64);
        sm.z += __shfl_xor(sm.z, off, 64);
        sm.w += __shfl_xor(sm.w, off, 64);
    }
    if (lane == 0) red[wv] = sm;
    __syncthreads();
    float4 inv;
    {
        float4 r0 = red[0], r1 = red[1], r2 = red[2], r3 = red[3];
        // max element contributes exp(0)=1 -> sums are strictly positive
        inv.x = 1.f / (r0.x + r1.x + r2.x + r3.x);
        inv.y = 1.f / (r0.y + r1.y + r2.y + r3.y);
        inv.z = 1.f / (r0.z + r1.z + r2.z + r3.z);
        inv.w = 1.f / (r0.w + r1.w + r2.w + r3.w);
    }

    // ---- pass 3: chunked avg-attn weights + weighted sum over segment ----
    float acc = 0.f;
    for (int c = 0; c < len; c += 256) {
        float w = 0.f;
        if (c + t < len) {
            float4 s = scores4[start + c + t];
            w = 0.25f * (expf(s.x - mx.x) * inv.x + expf(s.y - mx.y) * inv.y +
                         expf(s.z - mx.z) * inv.z + expf(s.w - mx.w) * inv.w);
        }
        __syncthreads();              // previous chunk's readers done
        wl[t] = w;
        __syncthreads();
        const int cl = min(256, len - c);
        const float* xp = x + (size_t)(start + c) * 256 + t;
        int j = 0;
        for (; j + 8 <= cl; j += 8) {
            float xv[8];
#pragma unroll
            for (int jj = 0; jj < 8; ++jj) xv[jj] = xp[(size_t)(j + jj) * 256];
#pragma unroll
            for (int jj = 0; jj < 8; ++jj) acc += wl[j + jj] * xv[jj];
        }
        for (; j < cl; ++j) acc += wl[j] * xp[(size_t)j * 256];
    }
    og[t] = acc;
}

extern "C" void kernel_launch(void* const* d_in, const int* in_sizes, int n_in,
                              void* d_out, int out_size, void* d_ws, size_t ws_size,
                              hipStream_t stream) {
    const float* x  = (const float*)d_in[0];
    const int* seg  = (const int*)d_in[1];
    // d_in[2] = num_graphs scalar (G=1024, fixed by problem)
    const float* W1 = (const float*)d_in[3];
    const float* b1 = (const float*)d_in[4];
    const float* W2 = (const float*)d_in[5];
    const float* b2 = (const float*)d_in[6];
    float* out = (float*)d_out;

    const int N = in_sizes[0] / 256;     // 200000
    const int G = 1024;

    char* ws = (char*)d_ws;
    float* scores = (float*)ws;                                  // N*4 fp32 = 3.2 MB
    u16* W1T      = (u16*)(ws + (size_t)N * 16);                 // 131072 u16 = 256 KB
    int* starts   = (int*)(ws + (size_t)N * 16 + 262144);        // (G+1) int

    transpose_w1<<<16, 256, 0, stream>>>(W1, W1T);
    starts_kernel<<<(G + 256) / 256, 256, 0, stream>>>(seg, starts, N, G);
    score_kernel<<<(N + 63) / 64, 256, 0, stream>>>(x, W1T, b1, W2, b2, scores, N);
    pool_kernel<<<G, 256, 0, stream>>>(x, (const float4*)scores, starts, out);
}